// Round 7
// baseline (381.275 us; speedup 1.0000x reference)
//
#include <hip/hip_runtime.h>
#include <hip/hip_bf16.h>

// Problem constants (match reference setup_inputs)
#define Nn 50000
#define Ee 800000
#define Gg 256
#define VOC 120
#define DH 100
#define CAPc 25
#define NTYPE 119          // types 1..119
#define NCHUNK 196         // ceil(50000/256)
#define DR 4               // node ranges (12500 nodes each)
#define DS 32              // edge slices (25000 edges each)
#define DWORDS 6250        // 12500 nodes / 2 per 32-bit word (16-bit packed counts)

// ---------------- T = embed @ gcn_w : [120][100] ----------------
__global__ void t_kernel(const float* __restrict__ embed, const float* __restrict__ gcn_w,
                         float* __restrict__ T) {
    int t = blockIdx.x;
    int j = threadIdx.x;
    if (j < DH) {
        float acc = 0.f;
#pragma unroll
        for (int k = 0; k < 32; ++k) acc = fmaf(embed[t * 32 + k], gcn_w[k * DH + j], acc);
        T[t * DH + j] = acc;
    }
}

// ---------------- selection: first 25 nodes per (type, side) ----------------
__global__ void selcount_kernel(const int* __restrict__ feat_src, const int* __restrict__ feat_tar,
                                int* __restrict__ chunkcnt) {
    int chunk = blockIdx.x, side = blockIdx.y;
    const int* f = side ? feat_tar : feat_src;
    __shared__ int hist[VOC];
    int tid = threadIdx.x;
    if (tid < VOC) hist[tid] = 0;
    __syncthreads();
    int i = chunk * 256 + tid;
    if (i < Nn) atomicAdd(&hist[f[i]], 1);
    __syncthreads();
    if (tid < VOC) chunkcnt[(side * NCHUNK + chunk) * VOC + tid] = hist[tid];
}

// one wave per (side,type): parallel prefix over 196 chunk counts
__global__ __launch_bounds__(64) void selprefix_kernel(const int* __restrict__ chunkcnt,
                                                       int* __restrict__ base,
                                                       int* __restrict__ fullcnt) {
    int pair = blockIdx.x;  // 0..239
    int side = pair / VOC, t = pair - side * VOC;
    int lane = threadIdx.x;
    int run = 0;
    for (int c0 = 0; c0 < NCHUNK; c0 += 64) {
        int c = c0 + lane;
        int v = (c < NCHUNK) ? chunkcnt[(side * NCHUNK + c) * VOC + t] : 0;
        int inc = v;
#pragma unroll
        for (int o = 1; o < 64; o <<= 1) {
            int u = __shfl_up(inc, o, 64);
            if (lane >= o) inc += u;
        }
        if (c < NCHUNK) base[(side * NCHUNK + c) * VOC + t] = run + inc - v;
        run += __shfl(inc, 63, 64);
    }
    if (lane == 0) fullcnt[side * VOC + t] = run;
}

// writes selpos[node] = (t-1)*25 + rank for the first 25 nodes of each type (else stays -1)
__global__ void selgather_kernel(const int* __restrict__ feat_src, const int* __restrict__ feat_tar,
                                 const int* __restrict__ base, int* __restrict__ selpos_src,
                                 int* __restrict__ selpos_tar) {
    int chunk = blockIdx.x, side = blockIdx.y;
    const int* f = side ? feat_tar : feat_src;
    int* selpos = side ? selpos_tar : selpos_src;
    __shared__ int types[256];
    int tid = threadIdx.x;
    int i = chunk * 256 + tid;
    int t = (i < Nn) ? f[i] : -1;
    types[tid] = t;
    int bv = 0;
    bool need = (t >= 1);
    if (need) {
        bv = base[(side * NCHUNK + chunk) * VOC + t];
        need = (bv < CAPc);
    }
    int any = __syncthreads_count((int)need);  // also the barrier making types[] visible
    if (any == 0) return;                      // ~97% of blocks exit here
    if (need) {
        int rank = bv;
        for (int q = 0; q < 256; ++q)
            if (q < tid && types[q] == t) rank++;
        if (rank < CAPc) selpos[i] = (t - 1) * CAPc + rank;
    }
}

// ---------------- degree histograms: 2-level, atomic-free in global ----------------
__global__ __launch_bounds__(256) void deghist_kernel(
        const int* __restrict__ ei0, const int* __restrict__ ei1, const int* __restrict__ ei2,
        int* __restrict__ partial) {
    int job = blockIdx.y, g = job >> 1, isdst = job & 1;
    int r = blockIdx.x & (DR - 1), s = blockIdx.x >> 2;
    const int* ei = (g == 0) ? ei0 : (g == 1) ? ei1 : ei2;
    const uint4* a4 = (const uint4*)(ei + (isdst ? Ee : 0) + s * (Ee / DS));
    __shared__ int hist[DWORDS];
    int tid = threadIdx.x;
    for (int i = tid; i < DWORDS; i += 256) hist[i] = 0;
    __syncthreads();
    unsigned base = r * (2 * DWORDS);
    for (int idx = tid; idx < (Ee / DS) / 4; idx += 256) {  // ~24 iters
        uint4 v = a4[idx];
        unsigned q;
        q = v.x - base; if (q < 2 * DWORDS) atomicAdd(&hist[q >> 1], 1 << ((q & 1) * 16));
        q = v.y - base; if (q < 2 * DWORDS) atomicAdd(&hist[q >> 1], 1 << ((q & 1) * 16));
        q = v.z - base; if (q < 2 * DWORDS) atomicAdd(&hist[q >> 1], 1 << ((q & 1) * 16));
        q = v.w - base; if (q < 2 * DWORDS) atomicAdd(&hist[q >> 1], 1 << ((q & 1) * 16));
    }
    __syncthreads();
    int* outp = partial + ((size_t)(job * DR + r) * DS + s) * DWORDS;
    for (int i = tid; i < DWORDS; i += 256) outp[i] = hist[i];
}

// merge 32 packed partials per word; emit pc (src jobs) / rs (dst jobs).
__global__ __launch_bounds__(256) void degmerge_kernel(
        const int* __restrict__ partial,
        const int* __restrict__ feat0, const int* __restrict__ feat1, const int* __restrict__ feat2,
        const float* __restrict__ mask, float2* __restrict__ pc, float* __restrict__ rs) {
    int idx = blockIdx.x * 256 + threadIdx.x;
    if (idx >= 6 * DR * DWORDS) return;
    int job = idx / (DR * DWORDS);
    int rem = idx - job * (DR * DWORDS);
    int r = rem / DWORDS, w = rem - r * DWORDS;
    int g = job >> 1, isdst = job & 1;
    const int* p = partial + ((size_t)(job * DR + r) * DS) * DWORDS + w;
    int sum = 0;
#pragma unroll 8
    for (int s = 0; s < DS; ++s) sum += p[s * DWORDS];  // packed 16-bit fields, no overflow
    int c0 = sum & 0xFFFF, c1 = sum >> 16;
    int n0 = r * (2 * DWORDS) + 2 * w;
    if (isdst) {
        float2 v = make_float2(rsqrtf((float)max(c0, 1)), rsqrtf((float)max(c1, 1)));
        ((float2*)(rs + (size_t)g * Nn))[r * DWORDS + w] = v;
    } else {
        const int* ft = (g == 0) ? feat0 : (g == 1) ? feat1 : feat2;
        float cf0 = rsqrtf((float)max(c0, 1));
        float cf1 = rsqrtf((float)max(c1, 1));
        if (g == 0) {
            cf0 *= mask[n0];
            cf1 *= mask[n0 + 1];
        }
        float4 v = make_float4(cf0, __int_as_float(ft[n0]), cf1, __int_as_float(ft[n0 + 1]));
        ((float4*)(pc + (size_t)g * Nn))[r * DWORDS + w] = v;
    }
}

// ---------------- W[g][dst][type] += coef[src]; 4 edges/thread, all 3 graphs ----------
__global__ __launch_bounds__(256) void wacc_kernel(const int* __restrict__ ei0,
                                                   const int* __restrict__ ei1,
                                                   const int* __restrict__ ei2,
                                                   const float2* __restrict__ pc,
                                                   float* __restrict__ W) {
    int g = blockIdx.y;
    const int* ei = (g == 0) ? ei0 : (g == 1) ? ei1 : ei2;
    const float2* pcg = pc + (size_t)g * Nn;
    float* Wg = W + (size_t)g * Nn * VOC;
    int i = blockIdx.x * 256 + threadIdx.x;
    int e0 = i * 4;
    if (e0 < Ee) {
        uint4 s4 = *(const uint4*)&ei[e0];
        uint4 d4 = *(const uint4*)&ei[Ee + e0];
        float2 p0 = pcg[s4.x];
        float2 p1 = pcg[s4.y];
        float2 p2 = pcg[s4.z];
        float2 p3 = pcg[s4.w];
        atomicAdd(&Wg[(size_t)d4.x * VOC + __float_as_int(p0.y)], p0.x);
        atomicAdd(&Wg[(size_t)d4.y * VOC + __float_as_int(p1.y)], p1.x);
        atomicAdd(&Wg[(size_t)d4.z * VOC + __float_as_int(p2.y)], p2.x);
        atomicAdd(&Wg[(size_t)d4.w * VOC + __float_as_int(p3.y)], p3.x);
    }
}

// ---------------- h = relu((W@T)*rs + b); fused pool-max; scatter selected rows ------
// No LDS staging: W rows are wave-broadcast loads (L1), T is L2-resident.
// 256 threads, 64 rows/block, 8 rows x 4 cols per thread; grid.y = graph.
__global__ __launch_bounds__(256, 4) void h_kernel(const float* __restrict__ Wall,
                                                   const float* __restrict__ T,
                                                   const float* __restrict__ rsall,
                                                   const int* __restrict__ selposall,
                                                   float* __restrict__ h_sel,
                                                   const float* __restrict__ gcn_b,
                                                   float* __restrict__ pool) {
    __shared__ float pl[2 * DH];
    __shared__ int sp_l[64];
    int g = blockIdx.y;
    const float* Wg = Wall + (size_t)g * Nn * VOC;
    const float* rs = rsall + (size_t)g * Nn;
    const int* selpos = (g == 0) ? nullptr : selposall + (size_t)(g - 1) * Nn;
    float* hs = h_sel + (size_t)(g == 2 ? NTYPE * CAPc * DH : 0);
    float* poolg = pool + g * (Gg * DH);

    int tid = threadIdx.x;
    int r0 = blockIdx.x * 64;
    if (tid < 2 * DH) pl[tid] = 0.f;
    if (tid < 64) {
        int row = r0 + tid;
        sp_l[tid] = (selpos != nullptr && row < Nn) ? selpos[row] : -1;
    }
    __syncthreads();

    int tc = tid & 31, tr = tid >> 5;
    int c0 = (tc < 25 ? tc : 24) * 4;  // lanes 25..31 duplicate lane 24 (results unused)
    const float* Wr = Wg + (size_t)(r0 + tr * 8) * VOC;
    float4 acc[8];
#pragma unroll
    for (int u = 0; u < 8; ++u) acc[u] = make_float4(0.f, 0.f, 0.f, 0.f);

#pragma unroll 2
    for (int tq = 0; tq < 30; ++tq) {
        float4 tv0 = *(const float4*)&T[(tq * 4 + 0) * DH + c0];
        float4 tv1 = *(const float4*)&T[(tq * 4 + 1) * DH + c0];
        float4 tv2 = *(const float4*)&T[(tq * 4 + 2) * DH + c0];
        float4 tv3 = *(const float4*)&T[(tq * 4 + 3) * DH + c0];
#pragma unroll
        for (int u = 0; u < 8; ++u) {
            float4 wv = *(const float4*)&Wr[u * VOC + tq * 4];  // wave-broadcast
            acc[u].x = fmaf(wv.x, tv0.x, fmaf(wv.y, tv1.x, fmaf(wv.z, tv2.x, fmaf(wv.w, tv3.x, acc[u].x))));
            acc[u].y = fmaf(wv.x, tv0.y, fmaf(wv.y, tv1.y, fmaf(wv.z, tv2.y, fmaf(wv.w, tv3.y, acc[u].y))));
            acc[u].z = fmaf(wv.x, tv0.z, fmaf(wv.y, tv1.z, fmaf(wv.z, tv2.z, fmaf(wv.w, tv3.z, acc[u].z))));
            acc[u].w = fmaf(wv.x, tv0.w, fmaf(wv.y, tv1.w, fmaf(wv.z, tv2.w, fmaf(wv.w, tv3.w, acc[u].w))));
        }
    }

    int gb0 = (r0 * Gg) / Nn;
    if (tc < 25) {
        float4 bias = *(const float4*)&gcn_b[c0];
        float4 pm = make_float4(0.f, 0.f, 0.f, 0.f);
        int curgl = 0;
#pragma unroll
        for (int u = 0; u < 8; ++u) {
            int row = r0 + tr * 8 + u;
            if (row < Nn) {
                float sc = rs[row];
                float4 v;
                v.x = fmaxf(fmaf(acc[u].x, sc, bias.x), 0.f);
                v.y = fmaxf(fmaf(acc[u].y, sc, bias.y), 0.f);
                v.z = fmaxf(fmaf(acc[u].z, sc, bias.z), 0.f);
                v.w = fmaxf(fmaf(acc[u].w, sc, bias.w), 0.f);
                int sp = sp_l[tr * 8 + u];
                if (sp >= 0) *(float4*)&hs[(size_t)sp * DH + c0] = v;
                int gl = (row * Gg) / Nn - gb0;
                if (gl != curgl) {  // rows are consecutive -> at most one switch
                    atomicMax((int*)&pl[curgl * DH + c0 + 0], __float_as_int(pm.x));
                    atomicMax((int*)&pl[curgl * DH + c0 + 1], __float_as_int(pm.y));
                    atomicMax((int*)&pl[curgl * DH + c0 + 2], __float_as_int(pm.z));
                    atomicMax((int*)&pl[curgl * DH + c0 + 3], __float_as_int(pm.w));
                    pm = v;
                    curgl = gl;
                } else {
                    pm.x = fmaxf(pm.x, v.x);
                    pm.y = fmaxf(pm.y, v.y);
                    pm.z = fmaxf(pm.z, v.z);
                    pm.w = fmaxf(pm.w, v.w);
                }
            }
        }
        atomicMax((int*)&pl[curgl * DH + c0 + 0], __float_as_int(pm.x));
        atomicMax((int*)&pl[curgl * DH + c0 + 1], __float_as_int(pm.y));
        atomicMax((int*)&pl[curgl * DH + c0 + 2], __float_as_int(pm.z));
        atomicMax((int*)&pl[curgl * DH + c0 + 3], __float_as_int(pm.w));
    }
    __syncthreads();
    int lastrow = min(r0 + 63, Nn - 1);
    int ng = (lastrow * Gg) / Nn - gb0 + 1;
    if (tid < DH * ng) {
        int gl = tid / DH, c = tid % DH;
        atomicMax((int*)&poolg[(gb0 + gl) * DH + c], __float_as_int(pl[gl * DH + c]));
    }
}

// ---------------- pooled GEMMs + defect prob ----------------
__global__ void poolgemm_kernel(const float* __restrict__ pool, const float* __restrict__ fc_w,
                                const float* __restrict__ fc_b, const float* __restrict__ def_w,
                                const float* __restrict__ def_b, float* __restrict__ out) {
    int g = blockIdx.x;
    __shared__ float xb[32];
    int tid = threadIdx.x;  // 128
    if (tid < 96) {
        int p = tid >> 5, j = tid & 31;
        float acc = fc_b[j];
        const float* pr = pool + p * (Gg * DH) + g * DH;
#pragma unroll 4
        for (int k = 0; k < DH; ++k) acc = fmaf(pr[k], fc_w[k * 32 + j], acc);
        int off = (p == 0) ? 0 : (p == 1 ? 8448 : 16640);
        out[off + g * 32 + j] = acc;
        if (p == 0) xb[j] = acc;
    }
    __syncthreads();
    if (tid < 32) {
        float v = xb[tid] * def_w[tid];
        for (int o = 16; o; o >>= 1) v += __shfl_down(v, o, 64);
        if (tid == 0) out[8192 + g] = 1.f / (1.f + expf(-(v + def_b[0])));
    }
}

// ---------------- X features for selected rows: X[type][50][32] ----------------
__global__ __launch_bounds__(256) void xfeat_kernel(const float* __restrict__ h_sel,
                                                    const int* __restrict__ fullcnt,
                                                    const float* __restrict__ fc_w,
                                                    const float* __restrict__ fc_b,
                                                    float* __restrict__ X) {
    int t = blockIdx.x;  // type t+1
    __shared__ float fw[DH * 32];
    for (int i = threadIdx.x; i < DH * 32; i += 256) fw[i] = fc_w[i];
    __syncthreads();
    int cs = min(fullcnt[t + 1], CAPc);
    int ct = min(fullcnt[VOC + t + 1], CAPc);
    int j = threadIdx.x & 31, rg = threadIdx.x >> 5;
    for (int r = rg; r < 2 * CAPc; r += 8) {
        int side = r / CAPc, rr = r % CAPc;
        int cnt = side ? ct : cs;
        float acc = 0.f;
        if (rr < cnt) {
            const float* hr = h_sel + ((size_t)side * NTYPE * CAPc + (size_t)t * CAPc + rr) * DH;
            acc = fc_b[j];
#pragma unroll 4
            for (int k = 0; k < DH; ++k) acc = fmaf(hr[k], fw[k * 32 + j], acc);
        }
        X[(size_t)t * 1600 + r * 32 + j] = acc;
    }
}

// ---------------- per-type MMD ----------------
__device__ __forceinline__ float block_reduce256(float v, float* red, int tid) {
    __syncthreads();
    red[tid] = v;
    __syncthreads();
    for (int s = 128; s > 0; s >>= 1) {
        if (tid < s) red[tid] += red[tid + s];
        __syncthreads();
    }
    return red[0];
}

__global__ __launch_bounds__(256) void mmd_kernel(const float* __restrict__ X,
                                                  const int* __restrict__ fullcnt,
                                                  float* __restrict__ losses) {
    int t = blockIdx.x;  // type t+1
    __shared__ float Xs[50 * 32];
    __shared__ float D2[50 * 50];
    __shared__ float red[256];
    int tid = threadIdx.x;
    for (int i = tid; i < 1600; i += 256) Xs[i] = X[(size_t)t * 1600 + i];
    __syncthreads();
    int scF = fullcnt[t + 1];
    int tcF = fullcnt[VOC + t + 1];
    int m = min(scF, CAPc), n2 = min(tcF, CAPc);
    float bwpart = 0.f;
    for (int idx = tid; idx < 2500; idx += 256) {
        int i = idx / 50, j = idx % 50;
        float d = 0.f;
#pragma unroll
        for (int k = 0; k < 32; ++k) {
            float df = Xs[i * 32 + k] - Xs[j * 32 + k];
            d = fmaf(df, df, d);
        }
        D2[idx] = d;
        bool vi = (i < CAPc) ? (i < m) : (i - CAPc < n2);
        bool vj = (j < CAPc) ? (j < m) : (j - CAPc < n2);
        if (vi && vj) bwpart += d;
    }
    float bwsum = block_reduce256(bwpart, red, tid);
    float ntot = (float)(m + n2);
    float bw = bwsum / fmaxf(ntot * ntot - ntot, 1.f) * 0.25f;  // / KER_MUL^(KER_NUM//2)
    float bws[5];
#pragma unroll
    for (int k = 0; k < 5; ++k) bws[k] = fmaxf(bw * (float)(1 << k), 1e-8f);
    float xx = 0.f, yy = 0.f, xy = 0.f;
    for (int idx = tid; idx < 2500; idx += 256) {
        int i = idx / 50, j = idx % 50;
        bool vi = (i < CAPc) ? (i < m) : (i - CAPc < n2);
        bool vj = (j < CAPc) ? (j < m) : (j - CAPc < n2);
        if (!(vi && vj)) continue;
        float d = D2[idx];
        float kv = 0.f;
#pragma unroll
        for (int k = 0; k < 5; ++k) kv += expf(-d / bws[k]);
        if (i < CAPc && j < CAPc) xx += kv;
        else if (i >= CAPc && j >= CAPc) yy += kv;
        else if (i < CAPc) xy += kv;
    }
    float rxx = block_reduce256(xx, red, tid);
    float ryy = block_reduce256(yy, red, tid);
    float rxy = block_reduce256(xy, red, tid);
    if (tid == 0) {
        float fm = (float)m, fn = (float)n2;
        float XX = rxx / fmaxf(fm * fm, 1.f);
        float YY = ryy / fmaxf(fn * fn, 1.f);
        float XY = rxy / fmaxf(fm * fn, 1.f);
        float loss = XX + YY - 2.f * XY;
        int inc = (scF >= 5 && tcF >= 5) ? 1 : 0;
        losses[t * 2 + 0] = inc ? loss : 0.f;
        losses[t * 2 + 1] = (float)inc;
    }
}

__global__ void final_kernel(const float* __restrict__ losses, float* __restrict__ out) {
    __shared__ float red[128], redc[128];
    int tid = threadIdx.x;
    float s = 0.f, c = 0.f;
    for (int t = tid; t < NTYPE; t += 128) {
        s += losses[t * 2];
        c += losses[t * 2 + 1];
    }
    red[tid] = s;
    redc[tid] = c;
    __syncthreads();
    for (int st = 64; st > 0; st >>= 1) {
        if (tid < st) {
            red[tid] += red[tid + st];
            redc[tid] += redc[tid + st];
        }
        __syncthreads();
    }
    if (tid == 0) out[24832] = redc[0] > 0.f ? red[0] / fmaxf(redc[0], 1.f) : 0.f;
}

extern "C" void kernel_launch(void* const* d_in, const int* in_sizes, int n_in,
                              void* d_out, int out_size, void* d_ws, size_t ws_size,
                              hipStream_t stream) {
    const int* feat = (const int*)d_in[0];
    const int* feat_src = (const int*)d_in[1];
    const int* feat_tar = (const int*)d_in[2];
    const int* ei0 = (const int*)d_in[3];
    const int* ei1 = (const int*)d_in[4];
    const int* ei2 = (const int*)d_in[5];
    const float* mask = (const float*)d_in[7];
    const float* embed = (const float*)d_in[8];
    const float* gcn_w = (const float*)d_in[9];
    const float* gcn_b = (const float*)d_in[10];
    const float* fc_w = (const float*)d_in[11];
    const float* fc_b = (const float*)d_in[12];
    const float* def_w = (const float*)d_in[13];
    const float* def_b = (const float*)d_in[14];
    float* out = (float*)d_out;

    char* wsb = (char*)d_ws;
    float* W = (float*)(wsb + 0);               // 72,000,000 (3 x 24 MB)
    int* partial = (int*)(wsb + 0);             // 19,200,000 (aliases W; used before W's memset)
    float* T = (float*)(wsb + 72000000);        // 48,000
    float* pool = (float*)(wsb + 72048000);     // 307,200
    float2* pc = (float2*)(wsb + 72355200);     // 1,200,000 (3 x 50000 x 8B)
    float* rs = (float*)(wsb + 73555200);       // 600,000   (3 x 50000 x 4B)
    int* selpos = (int*)(wsb + 74155200);       // 400,000   (src then tar)
    float* h_sel = (float*)(wsb + 74555200);    // 2,380,000 (2 x 119 x 25 x 100 f32)
    int* fullcnt = (int*)(wsb + 76935200);      // 960
    float* X = (float*)(wsb + 76936160);        // 761,600
    float* losses = (float*)(wsb + 77697760);   // 952
    int* chunkcnt = (int*)(wsb + 77698720);     // 188,160
    int* baseb = (int*)(wsb + 77886880);        // 188,160  -> total ~78.1 MB (ws ~256 MB)

    hipMemsetAsync(pool, 0, 3 * Gg * DH * sizeof(float), stream);
    hipMemsetAsync(selpos, 0xFF, 2 * Nn * sizeof(int), stream);  // -1

    t_kernel<<<VOC, 128, 0, stream>>>(embed, gcn_w, T);

    selcount_kernel<<<dim3(NCHUNK, 2), 256, 0, stream>>>(feat_src, feat_tar, chunkcnt);
    selprefix_kernel<<<2 * VOC, 64, 0, stream>>>(chunkcnt, baseb, fullcnt);
    selgather_kernel<<<dim3(NCHUNK, 2), 256, 0, stream>>>(feat_src, feat_tar, baseb,
                                                          selpos, selpos + Nn);

    deghist_kernel<<<dim3(DR * DS, 6), 256, 0, stream>>>(ei0, ei1, ei2, partial);
    degmerge_kernel<<<(6 * DR * DWORDS + 255) / 256, 256, 0, stream>>>(partial, feat, feat_src,
                                                                       feat_tar, mask, pc, rs);

    hipMemsetAsync(W, 0, 3 * (size_t)Nn * VOC * sizeof(float), stream);
    wacc_kernel<<<dim3((Ee / 4 + 255) / 256, 3), 256, 0, stream>>>(ei0, ei1, ei2, pc, W);
    h_kernel<<<dim3((Nn + 63) / 64, 3), 256, 0, stream>>>(W, T, rs, selpos, h_sel, gcn_b, pool);

    poolgemm_kernel<<<Gg, 128, 0, stream>>>(pool, fc_w, fc_b, def_w, def_b, out);
    xfeat_kernel<<<NTYPE, 256, 0, stream>>>(h_sel, fullcnt, fc_w, fc_b, X);
    mmd_kernel<<<NTYPE, 256, 0, stream>>>(X, fullcnt, losses);
    final_kernel<<<1, 128, 0, stream>>>(losses, out);
}

// Round 8
// 265.571 us; speedup vs baseline: 1.4357x; 1.4357x over previous
//
#include <hip/hip_runtime.h>
#include <hip/hip_bf16.h>

// Problem constants (match reference setup_inputs)
#define Nn 50000
#define Ee 800000
#define Gg 256
#define VOC 120
#define DH 100
#define CAPc 25
#define NTYPE 119          // types 1..119
#define NCHUNK 196         // ceil(50000/256)
#define DR 4               // node ranges for degree histogram
#define DS 32              // edge slices for degree histogram
#define DWORDS 6250        // 12500 nodes / 2 per word (16-bit packed counts)
#define NBIN 391           // ceil(50000/128) dst bins (128 nodes each)
#define EBLK 782           // edge blocks (1024 edges each): 782*1024 >= 800000

// ---------------- T = embed @ gcn_w : [120][100] ----------------
__global__ void t_kernel(const float* __restrict__ embed, const float* __restrict__ gcn_w,
                         float* __restrict__ T) {
    int t = blockIdx.x;
    int j = threadIdx.x;
    if (j < DH) {
        float acc = 0.f;
#pragma unroll
        for (int k = 0; k < 32; ++k) acc = fmaf(embed[t * 32 + k], gcn_w[k * DH + j], acc);
        T[t * DH + j] = acc;
    }
}

// ---------------- selection: first 25 nodes per (type, side) ----------------
__global__ void selcount_kernel(const int* __restrict__ feat_src, const int* __restrict__ feat_tar,
                                int* __restrict__ chunkcnt) {
    int chunk = blockIdx.x, side = blockIdx.y;
    const int* f = side ? feat_tar : feat_src;
    __shared__ int hist[VOC];
    int tid = threadIdx.x;
    if (tid < VOC) hist[tid] = 0;
    __syncthreads();
    int i = chunk * 256 + tid;
    if (i < Nn) atomicAdd(&hist[f[i]], 1);
    __syncthreads();
    if (tid < VOC) chunkcnt[(side * NCHUNK + chunk) * VOC + tid] = hist[tid];
}

// one wave per (side,type): parallel prefix over 196 chunk counts
__global__ __launch_bounds__(64) void selprefix_kernel(const int* __restrict__ chunkcnt,
                                                       int* __restrict__ base,
                                                       int* __restrict__ fullcnt) {
    int pair = blockIdx.x;  // 0..239
    int side = pair / VOC, t = pair - side * VOC;
    int lane = threadIdx.x;
    int run = 0;
    for (int c0 = 0; c0 < NCHUNK; c0 += 64) {
        int c = c0 + lane;
        int v = (c < NCHUNK) ? chunkcnt[(side * NCHUNK + c) * VOC + t] : 0;
        int inc = v;
#pragma unroll
        for (int o = 1; o < 64; o <<= 1) {
            int u = __shfl_up(inc, o, 64);
            if (lane >= o) inc += u;
        }
        if (c < NCHUNK) base[(side * NCHUNK + c) * VOC + t] = run + inc - v;
        run += __shfl(inc, 63, 64);
    }
    if (lane == 0) fullcnt[side * VOC + t] = run;
}

// writes selpos[node] = (t-1)*25 + rank for the first 25 nodes of each type (else stays -1)
__global__ void selgather_kernel(const int* __restrict__ feat_src, const int* __restrict__ feat_tar,
                                 const int* __restrict__ base, int* __restrict__ selpos_src,
                                 int* __restrict__ selpos_tar) {
    int chunk = blockIdx.x, side = blockIdx.y;
    const int* f = side ? feat_tar : feat_src;
    int* selpos = side ? selpos_tar : selpos_src;
    __shared__ int types[256];
    int tid = threadIdx.x;
    int i = chunk * 256 + tid;
    int t = (i < Nn) ? f[i] : -1;
    types[tid] = t;
    int bv = 0;
    bool need = (t >= 1);
    if (need) {
        bv = base[(side * NCHUNK + chunk) * VOC + t];
        need = (bv < CAPc);
    }
    int any = __syncthreads_count((int)need);
    if (any == 0) return;  // ~97% of blocks exit here
    if (need) {
        int rank = bv;
        for (int q = 0; q < 256; ++q)
            if (q < tid && types[q] == t) rank++;
        if (rank < CAPc) selpos[i] = (t - 1) * CAPc + rank;
    }
}

// ---------------- degree histograms (for pc/rs): 2-level, atomic-free ----------------
__global__ __launch_bounds__(256) void deghist_kernel(
        const int* __restrict__ ei0, const int* __restrict__ ei1, const int* __restrict__ ei2,
        int* __restrict__ partial) {
    int job = blockIdx.y, g = job >> 1, isdst = job & 1;
    int r = blockIdx.x & (DR - 1), s = blockIdx.x >> 2;
    const int* ei = (g == 0) ? ei0 : (g == 1) ? ei1 : ei2;
    const uint4* a4 = (const uint4*)(ei + (isdst ? Ee : 0) + s * (Ee / DS));
    __shared__ int hist[DWORDS];
    int tid = threadIdx.x;
    for (int i = tid; i < DWORDS; i += 256) hist[i] = 0;
    __syncthreads();
    unsigned base = r * (2 * DWORDS);
    for (int idx = tid; idx < (Ee / DS) / 4; idx += 256) {
        uint4 v = a4[idx];
        unsigned q;
        q = v.x - base; if (q < 2 * DWORDS) atomicAdd(&hist[q >> 1], 1 << ((q & 1) * 16));
        q = v.y - base; if (q < 2 * DWORDS) atomicAdd(&hist[q >> 1], 1 << ((q & 1) * 16));
        q = v.z - base; if (q < 2 * DWORDS) atomicAdd(&hist[q >> 1], 1 << ((q & 1) * 16));
        q = v.w - base; if (q < 2 * DWORDS) atomicAdd(&hist[q >> 1], 1 << ((q & 1) * 16));
    }
    __syncthreads();
    int* outp = partial + ((size_t)(job * DR + r) * DS + s) * DWORDS;
    for (int i = tid; i < DWORDS; i += 256) outp[i] = hist[i];
}

__global__ __launch_bounds__(256) void degmerge_kernel(
        const int* __restrict__ partial,
        const int* __restrict__ feat0, const int* __restrict__ feat1, const int* __restrict__ feat2,
        const float* __restrict__ mask, float2* __restrict__ pc, float* __restrict__ rs) {
    int idx = blockIdx.x * 256 + threadIdx.x;
    if (idx >= 6 * DR * DWORDS) return;
    int job = idx / (DR * DWORDS);
    int rem = idx - job * (DR * DWORDS);
    int r = rem / DWORDS, w = rem - r * DWORDS;
    int g = job >> 1, isdst = job & 1;
    const int* p = partial + ((size_t)(job * DR + r) * DS) * DWORDS + w;
    int sum = 0;
#pragma unroll 8
    for (int s = 0; s < DS; ++s) sum += p[s * DWORDS];
    int c0 = sum & 0xFFFF, c1 = sum >> 16;
    int n0 = r * (2 * DWORDS) + 2 * w;
    if (isdst) {
        float2 v = make_float2(rsqrtf((float)max(c0, 1)), rsqrtf((float)max(c1, 1)));
        ((float2*)(rs + (size_t)g * Nn))[r * DWORDS + w] = v;
    } else {
        const int* ft = (g == 0) ? feat0 : (g == 1) ? feat1 : feat2;
        float cf0 = rsqrtf((float)max(c0, 1));
        float cf1 = rsqrtf((float)max(c1, 1));
        if (g == 0) {
            cf0 *= mask[n0];
            cf1 *= mask[n0 + 1];
        }
        float4 v = make_float4(cf0, __int_as_float(ft[n0]), cf1, __int_as_float(ft[n0 + 1]));
        ((float4*)(pc + (size_t)g * Nn))[r * DWORDS + w] = v;
    }
}

// ---------------- W construction: exact-offset dst-binning, NO global atomics --------
// A1: per-(block,bin) counts. bin = dst >> 7.
__global__ __launch_bounds__(256) void bincount_kernel(const int* __restrict__ ei0,
                                                       const int* __restrict__ ei1,
                                                       const int* __restrict__ ei2,
                                                       int* __restrict__ cntbuf) {
    int g = blockIdx.y;
    const int* dst = ((g == 0) ? ei0 : (g == 1) ? ei1 : ei2) + Ee;
    __shared__ int cnt[NBIN];
    int tid = threadIdx.x;
    for (int i = tid; i < NBIN; i += 256) cnt[i] = 0;
    __syncthreads();
    int e0 = (blockIdx.x * 256 + tid) * 4;
    if (e0 < Ee) {
        uint4 d = *(const uint4*)&dst[e0];
        atomicAdd(&cnt[d.x >> 7], 1);
        atomicAdd(&cnt[d.y >> 7], 1);
        atomicAdd(&cnt[d.z >> 7], 1);
        atomicAdd(&cnt[d.w >> 7], 1);
    }
    __syncthreads();
    for (int i = tid; i < NBIN; i += 256)
        cntbuf[((size_t)g * NBIN + i) * EBLK + blockIdx.x] = cnt[i];
}

// A2a: one wave per (g,bin): exclusive prefix over EBLK block counts -> ofs, bintot
__global__ __launch_bounds__(64) void binprefix_kernel(const int* __restrict__ cntbuf,
                                                       int* __restrict__ ofsbuf,
                                                       int* __restrict__ bintot) {
    int pair = blockIdx.x;  // 0..3*NBIN-1
    const int* src = cntbuf + (size_t)pair * EBLK;
    int* dst = ofsbuf + (size_t)pair * EBLK;
    int lane = threadIdx.x;
    int run = 0;
    for (int c0 = 0; c0 < EBLK; c0 += 64) {
        int c = c0 + lane;
        int v = (c < EBLK) ? src[c] : 0;
        int inc = v;
#pragma unroll
        for (int o = 1; o < 64; o <<= 1) {
            int u = __shfl_up(inc, o, 64);
            if (lane >= o) inc += u;
        }
        if (c < EBLK) dst[c] = run + inc - v;
        run += __shfl(inc, 63, 64);
    }
    if (lane == 0) bintot[pair] = run;
}

// A2b: one wave per graph: exclusive prefix over NBIN bin totals -> binbase
__global__ __launch_bounds__(64) void binbase_kernel(const int* __restrict__ bintot,
                                                     int* __restrict__ binbase) {
    int g = blockIdx.x;
    int lane = threadIdx.x;
    int run = 0;
    for (int c0 = 0; c0 < NBIN; c0 += 64) {
        int c = c0 + lane;
        int v = (c < NBIN) ? bintot[g * NBIN + c] : 0;
        int inc = v;
#pragma unroll
        for (int o = 1; o < 64; o <<= 1) {
            int u = __shfl_up(inc, o, 64);
            if (lane >= o) inc += u;
        }
        if (c < NBIN) binbase[g * NBIN + c] = run + inc - v;
        run += __shfl(inc, 63, 64);
    }
}

// A3: scatter edges into bins: ebuf word = (dst&127)<<16 | src
__global__ __launch_bounds__(256) void binscatter_kernel(const int* __restrict__ ei0,
                                                         const int* __restrict__ ei1,
                                                         const int* __restrict__ ei2,
                                                         const int* __restrict__ ofsbuf,
                                                         const int* __restrict__ binbase,
                                                         unsigned* __restrict__ ebuf) {
    int g = blockIdx.y;
    const int* ei = (g == 0) ? ei0 : (g == 1) ? ei1 : ei2;
    __shared__ int cur[NBIN];
    int tid = threadIdx.x;
    for (int i = tid; i < NBIN; i += 256)
        cur[i] = binbase[g * NBIN + i] + ofsbuf[((size_t)g * NBIN + i) * EBLK + blockIdx.x];
    __syncthreads();
    unsigned* eb = ebuf + (size_t)g * Ee;
    int e0 = (blockIdx.x * 256 + tid) * 4;
    if (e0 < Ee) {
        uint4 s = *(const uint4*)&ei[e0];
        uint4 d = *(const uint4*)&ei[Ee + e0];
        int p;
        p = atomicAdd(&cur[d.x >> 7], 1); eb[p] = ((d.x & 127u) << 16) | s.x;
        p = atomicAdd(&cur[d.y >> 7], 1); eb[p] = ((d.y & 127u) << 16) | s.y;
        p = atomicAdd(&cur[d.z >> 7], 1); eb[p] = ((d.z & 127u) << 16) | s.z;
        p = atomicAdd(&cur[d.w >> 7], 1); eb[p] = ((d.w & 127u) << 16) | s.w;
    }
}

// A4: one block per (bin,g): accumulate W slice in LDS, plain-store (replaces memset+atomics)
__global__ __launch_bounds__(256, 2) void waccum_kernel(const unsigned* __restrict__ ebuf,
                                                        const float2* __restrict__ pc,
                                                        const int* __restrict__ binbase,
                                                        const int* __restrict__ bintot,
                                                        float* __restrict__ W) {
    int g = blockIdx.y, bin = blockIdx.x;
    __shared__ float Wl[128 * VOC];  // 61440 B
    int tid = threadIdx.x;
    for (int i = tid; i < 128 * VOC; i += 256) Wl[i] = 0.f;
    __syncthreads();
    int base = binbase[g * NBIN + bin];
    int cnt = bintot[g * NBIN + bin];
    const unsigned* eb = ebuf + (size_t)g * Ee + base;
    const float2* pcg = pc + (size_t)g * Nn;
    for (int i = tid; i < cnt; i += 256) {
        unsigned e = eb[i];
        float2 p = pcg[e & 0xFFFFu];
        atomicAdd(&Wl[(e >> 16) * VOC + __float_as_int(p.y)], p.x);
    }
    __syncthreads();
    int r0 = bin * 128;
    int nr = min(128, Nn - r0);
    float4* Wg = (float4*)(W + ((size_t)g * Nn + r0) * VOC);
    int nq = nr * (VOC / 4);
    const float4* Wl4 = (const float4*)Wl;
    for (int i = tid; i < nq; i += 256) Wg[i] = Wl4[i];
}

// ---------------- sparse h: per-row nonzero (type,w) list; T in LDS ----------------
// h[row] = relu((sum_t W[row][t]*T[t]) * rs + b); fused pool-max + h_sel scatter.
// Block: 4 waves x 64 rows = 256 rows; ~16 nonzeros of 120 per W row.
__global__ __launch_bounds__(256, 3) void sparse_h_kernel(const float* __restrict__ Wall,
                                                          const float* __restrict__ T,
                                                          const float* __restrict__ rsall,
                                                          const int* __restrict__ selposall,
                                                          float* __restrict__ h_sel,
                                                          const float* __restrict__ gcn_b,
                                                          float* __restrict__ pool) {
    __shared__ float Tl[VOC * DH];   // 48000 B
    __shared__ float pl[3 * DH];     // block spans <=3 graph segments
    __shared__ float2 ls[4][120];    // per-wave (type_bits, w) list
    int g = blockIdx.y;
    const float* Wg = Wall + (size_t)g * Nn * VOC;
    const float* rs = rsall + (size_t)g * Nn;
    const int* selpos = (g == 0) ? nullptr : selposall + (size_t)(g - 1) * Nn;
    float* hs = h_sel + (size_t)(g == 2 ? NTYPE * CAPc * DH : 0);
    float* poolg = pool + g * (Gg * DH);

    int tid = threadIdx.x;
    float4* Tl4 = (float4*)Tl;
    const float4* Tg4 = (const float4*)T;
#pragma unroll
    for (int i = 0; i < 12; ++i) {
        int idx = tid + i * 256;
        if (idx < 3000) Tl4[idx] = Tg4[idx];
    }
    for (int i = tid; i < 3 * DH; i += 256) pl[i] = 0.f;
    __syncthreads();

    int r0 = blockIdx.x * 256;
    int gb0 = (r0 * Gg) / Nn;
    int wv = tid >> 6, lane = tid & 63;
    int rowbase = r0 + wv * 64;
    int cl2 = 2 * (lane < 50 ? lane : 49);
    float2 bias = *(const float2*)&gcn_b[cl2];

    // per-wave preload of rs/selpos for the 64 rows (coalesced), accessed via shfl
    int prow = rowbase + lane;
    float rs_l = (prow < Nn) ? rs[prow] : 1.f;
    int sp_l = (selpos != nullptr && prow < Nn) ? selpos[prow] : -1;

    float2 pm = make_float2(0.f, 0.f);
    int curgl = (rowbase < Nn) ? ((rowbase * Gg) / Nn - gb0) : 0;

    if (rowbase < Nn) {
        float2 w2 = (lane < 60) ? *(const float2*)&Wg[(size_t)rowbase * VOC + 2 * lane]
                                : make_float2(0.f, 0.f);
        for (int i = 0; i < 64; ++i) {
            int row = rowbase + i;
            if (row >= Nn) break;
            // prefetch next row's W
            float2 w2n = make_float2(0.f, 0.f);
            if (lane < 60 && row + 1 < Nn)
                w2n = *(const float2*)&Wg[(size_t)(row + 1) * VOC + 2 * lane];
            // build nonzero list
            unsigned long long m0 = __ballot(w2.x != 0.f);
            unsigned long long m1 = __ballot(w2.y != 0.f);
            int n0 = __popcll(m0);
            unsigned long long below = (lane == 0) ? 0ull : (~0ull >> (64 - lane));
            if (w2.x != 0.f) {
                int rk = __popcll(m0 & below);
                ls[wv][rk] = make_float2(__int_as_float(2 * lane), w2.x);
            }
            if (w2.y != 0.f) {
                int rk = n0 + __popcll(m1 & below);
                ls[wv][rk] = make_float2(__int_as_float(2 * lane + 1), w2.y);
            }
            int n = n0 + __popcll(m1);
            asm volatile("s_waitcnt lgkmcnt(0)" ::: "memory");  // cross-lane LDS visibility
            float2 acc = make_float2(0.f, 0.f);
            for (int k = 0; k < n; ++k) {
                float2 e = ls[wv][k];  // uniform-address broadcast read
                int t = __float_as_int(e.x);
                float2 tv = *(const float2*)&Tl[t * DH + cl2];
                acc.x = fmaf(e.y, tv.x, acc.x);
                acc.y = fmaf(e.y, tv.y, acc.y);
            }
            asm volatile("s_waitcnt lgkmcnt(0)" ::: "memory");  // drain reads before next writes
            // epilogue for this row
            if (lane < 50) {
                float sc = __shfl(rs_l, i, 64);
                float2 hv;
                hv.x = fmaxf(fmaf(acc.x, sc, bias.x), 0.f);
                hv.y = fmaxf(fmaf(acc.y, sc, bias.y), 0.f);
                int sp = __shfl(sp_l, i, 64);
                if (sp >= 0) *(float2*)&hs[(size_t)sp * DH + cl2] = hv;
                int gl = (row * Gg) / Nn - gb0;
                if (gl != curgl) {
                    atomicMax((int*)&pl[curgl * DH + cl2 + 0], __float_as_int(pm.x));
                    atomicMax((int*)&pl[curgl * DH + cl2 + 1], __float_as_int(pm.y));
                    pm = hv;
                    curgl = gl;
                } else {
                    pm.x = fmaxf(pm.x, hv.x);
                    pm.y = fmaxf(pm.y, hv.y);
                }
            }
            w2 = w2n;
        }
        if (lane < 50) {
            atomicMax((int*)&pl[curgl * DH + cl2 + 0], __float_as_int(pm.x));
            atomicMax((int*)&pl[curgl * DH + cl2 + 1], __float_as_int(pm.y));
        }
    }
    __syncthreads();
    int lastrow = min(r0 + 255, Nn - 1);
    int ng = (lastrow * Gg) / Nn - gb0 + 1;
    for (int idx = tid; idx < DH * ng; idx += 256) {
        int gl = idx / DH, c = idx - gl * DH;
        atomicMax((int*)&poolg[(gb0 + gl) * DH + c], __float_as_int(pl[gl * DH + c]));
    }
}

// ---------------- pooled GEMMs + defect prob ----------------
__global__ void poolgemm_kernel(const float* __restrict__ pool, const float* __restrict__ fc_w,
                                const float* __restrict__ fc_b, const float* __restrict__ def_w,
                                const float* __restrict__ def_b, float* __restrict__ out) {
    int g = blockIdx.x;
    __shared__ float xb[32];
    int tid = threadIdx.x;  // 128
    if (tid < 96) {
        int p = tid >> 5, j = tid & 31;
        float acc = fc_b[j];
        const float* pr = pool + p * (Gg * DH) + g * DH;
#pragma unroll 4
        for (int k = 0; k < DH; ++k) acc = fmaf(pr[k], fc_w[k * 32 + j], acc);
        int off = (p == 0) ? 0 : (p == 1 ? 8448 : 16640);
        out[off + g * 32 + j] = acc;
        if (p == 0) xb[j] = acc;
    }
    __syncthreads();
    if (tid < 32) {
        float v = xb[tid] * def_w[tid];
        for (int o = 16; o; o >>= 1) v += __shfl_down(v, o, 64);
        if (tid == 0) out[8192 + g] = 1.f / (1.f + expf(-(v + def_b[0])));
    }
}

// ---------------- X features for selected rows: X[type][50][32] ----------------
__global__ __launch_bounds__(256) void xfeat_kernel(const float* __restrict__ h_sel,
                                                    const int* __restrict__ fullcnt,
                                                    const float* __restrict__ fc_w,
                                                    const float* __restrict__ fc_b,
                                                    float* __restrict__ X) {
    int t = blockIdx.x;  // type t+1
    __shared__ float fw[DH * 32];
    for (int i = threadIdx.x; i < DH * 32; i += 256) fw[i] = fc_w[i];
    __syncthreads();
    int cs = min(fullcnt[t + 1], CAPc);
    int ct = min(fullcnt[VOC + t + 1], CAPc);
    int j = threadIdx.x & 31, rg = threadIdx.x >> 5;
    for (int r = rg; r < 2 * CAPc; r += 8) {
        int side = r / CAPc, rr = r % CAPc;
        int cnt = side ? ct : cs;
        float acc = 0.f;
        if (rr < cnt) {
            const float* hr = h_sel + ((size_t)side * NTYPE * CAPc + (size_t)t * CAPc + rr) * DH;
            acc = fc_b[j];
#pragma unroll 4
            for (int k = 0; k < DH; ++k) acc = fmaf(hr[k], fw[k * 32 + j], acc);
        }
        X[(size_t)t * 1600 + r * 32 + j] = acc;
    }
}

// ---------------- per-type MMD ----------------
__device__ __forceinline__ float block_reduce256(float v, float* red, int tid) {
    __syncthreads();
    red[tid] = v;
    __syncthreads();
    for (int s = 128; s > 0; s >>= 1) {
        if (tid < s) red[tid] += red[tid + s];
        __syncthreads();
    }
    return red[0];
}

__global__ __launch_bounds__(256) void mmd_kernel(const float* __restrict__ X,
                                                  const int* __restrict__ fullcnt,
                                                  float* __restrict__ losses) {
    int t = blockIdx.x;  // type t+1
    __shared__ float Xs[50 * 32];
    __shared__ float D2[50 * 50];
    __shared__ float red[256];
    int tid = threadIdx.x;
    for (int i = tid; i < 1600; i += 256) Xs[i] = X[(size_t)t * 1600 + i];
    __syncthreads();
    int scF = fullcnt[t + 1];
    int tcF = fullcnt[VOC + t + 1];
    int m = min(scF, CAPc), n2 = min(tcF, CAPc);
    float bwpart = 0.f;
    for (int idx = tid; idx < 2500; idx += 256) {
        int i = idx / 50, j = idx % 50;
        float d = 0.f;
#pragma unroll
        for (int k = 0; k < 32; ++k) {
            float df = Xs[i * 32 + k] - Xs[j * 32 + k];
            d = fmaf(df, df, d);
        }
        D2[idx] = d;
        bool vi = (i < CAPc) ? (i < m) : (i - CAPc < n2);
        bool vj = (j < CAPc) ? (j < m) : (j - CAPc < n2);
        if (vi && vj) bwpart += d;
    }
    float bwsum = block_reduce256(bwpart, red, tid);
    float ntot = (float)(m + n2);
    float bw = bwsum / fmaxf(ntot * ntot - ntot, 1.f) * 0.25f;  // / KER_MUL^(KER_NUM//2)
    float bws[5];
#pragma unroll
    for (int k = 0; k < 5; ++k) bws[k] = fmaxf(bw * (float)(1 << k), 1e-8f);
    float xx = 0.f, yy = 0.f, xy = 0.f;
    for (int idx = tid; idx < 2500; idx += 256) {
        int i = idx / 50, j = idx % 50;
        bool vi = (i < CAPc) ? (i < m) : (i - CAPc < n2);
        bool vj = (j < CAPc) ? (j < m) : (j - CAPc < n2);
        if (!(vi && vj)) continue;
        float d = D2[idx];
        float kv = 0.f;
#pragma unroll
        for (int k = 0; k < 5; ++k) kv += expf(-d / bws[k]);
        if (i < CAPc && j < CAPc) xx += kv;
        else if (i >= CAPc && j >= CAPc) yy += kv;
        else if (i < CAPc) xy += kv;
    }
    float rxx = block_reduce256(xx, red, tid);
    float ryy = block_reduce256(yy, red, tid);
    float rxy = block_reduce256(xy, red, tid);
    if (tid == 0) {
        float fm = (float)m, fn = (float)n2;
        float XX = rxx / fmaxf(fm * fm, 1.f);
        float YY = ryy / fmaxf(fn * fn, 1.f);
        float XY = rxy / fmaxf(fm * fn, 1.f);
        float loss = XX + YY - 2.f * XY;
        int inc = (scF >= 5 && tcF >= 5) ? 1 : 0;
        losses[t * 2 + 0] = inc ? loss : 0.f;
        losses[t * 2 + 1] = (float)inc;
    }
}

__global__ void final_kernel(const float* __restrict__ losses, float* __restrict__ out) {
    __shared__ float red[128], redc[128];
    int tid = threadIdx.x;
    float s = 0.f, c = 0.f;
    for (int t = tid; t < NTYPE; t += 128) {
        s += losses[t * 2];
        c += losses[t * 2 + 1];
    }
    red[tid] = s;
    redc[tid] = c;
    __syncthreads();
    for (int st = 64; st > 0; st >>= 1) {
        if (tid < st) {
            red[tid] += red[tid + st];
            redc[tid] += redc[tid + st];
        }
        __syncthreads();
    }
    if (tid == 0) out[24832] = redc[0] > 0.f ? red[0] / fmaxf(redc[0], 1.f) : 0.f;
}

extern "C" void kernel_launch(void* const* d_in, const int* in_sizes, int n_in,
                              void* d_out, int out_size, void* d_ws, size_t ws_size,
                              hipStream_t stream) {
    const int* feat = (const int*)d_in[0];
    const int* feat_src = (const int*)d_in[1];
    const int* feat_tar = (const int*)d_in[2];
    const int* ei0 = (const int*)d_in[3];
    const int* ei1 = (const int*)d_in[4];
    const int* ei2 = (const int*)d_in[5];
    const float* mask = (const float*)d_in[7];
    const float* embed = (const float*)d_in[8];
    const float* gcn_w = (const float*)d_in[9];
    const float* gcn_b = (const float*)d_in[10];
    const float* fc_w = (const float*)d_in[11];
    const float* fc_b = (const float*)d_in[12];
    const float* def_w = (const float*)d_in[13];
    const float* def_b = (const float*)d_in[14];
    float* out = (float*)d_out;

    char* wsb = (char*)d_ws;
    float* W = (float*)(wsb + 0);               // 72,000,000 (3 x 24 MB)
    int* partial = (int*)(wsb + 0);             // 19,200,000 (aliases W; used before W written)
    float* T = (float*)(wsb + 72000000);        // 48,000
    float* pool = (float*)(wsb + 72048000);     // 307,200
    float2* pc = (float2*)(wsb + 72355200);     // 1,200,000
    float* rs = (float*)(wsb + 73555200);       // 600,000
    int* selpos = (int*)(wsb + 74155200);       // 400,000 (src then tar)
    float* h_sel = (float*)(wsb + 74555200);    // 2,380,000
    int* fullcnt = (int*)(wsb + 76935200);      // 960
    float* X = (float*)(wsb + 76936160);        // 761,600
    float* losses = (float*)(wsb + 77697760);   // 952
    int* chunkcnt = (int*)(wsb + 77698720);     // 188,160
    int* baseb = (int*)(wsb + 77886880);        // 188,160
    int* cntbuf = (int*)(wsb + 78080000);       // 3,669,144 (3*391*782*4)
    int* ofsbuf = (int*)(wsb + 81750000);       // 3,669,144
    int* bintot = (int*)(wsb + 85420000);       // 4,692
    int* binbase = (int*)(wsb + 85425000);      // 4,692
    unsigned* ebuf = (unsigned*)(wsb + 85430000);  // 9,600,000 -> end ~95 MB (ws ~256 MB)

    hipMemsetAsync(pool, 0, 3 * Gg * DH * sizeof(float), stream);
    hipMemsetAsync(selpos, 0xFF, 2 * Nn * sizeof(int), stream);  // -1

    t_kernel<<<VOC, 128, 0, stream>>>(embed, gcn_w, T);

    selcount_kernel<<<dim3(NCHUNK, 2), 256, 0, stream>>>(feat_src, feat_tar, chunkcnt);
    selprefix_kernel<<<2 * VOC, 64, 0, stream>>>(chunkcnt, baseb, fullcnt);
    selgather_kernel<<<dim3(NCHUNK, 2), 256, 0, stream>>>(feat_src, feat_tar, baseb,
                                                          selpos, selpos + Nn);

    // W binning pipeline (no pc needed until waccum)
    bincount_kernel<<<dim3(EBLK, 3), 256, 0, stream>>>(ei0, ei1, ei2, cntbuf);
    binprefix_kernel<<<3 * NBIN, 64, 0, stream>>>(cntbuf, ofsbuf, bintot);
    binbase_kernel<<<3, 64, 0, stream>>>(bintot, binbase);
    binscatter_kernel<<<dim3(EBLK, 3), 256, 0, stream>>>(ei0, ei1, ei2, ofsbuf, binbase, ebuf);

    // degree coefficients (pc, rs); partial aliases W -> must precede waccum
    deghist_kernel<<<dim3(DR * DS, 6), 256, 0, stream>>>(ei0, ei1, ei2, partial);
    degmerge_kernel<<<(6 * DR * DWORDS + 255) / 256, 256, 0, stream>>>(partial, feat, feat_src,
                                                                       feat_tar, mask, pc, rs);

    waccum_kernel<<<dim3(NBIN, 3), 256, 0, stream>>>(ebuf, pc, binbase, bintot, W);
    sparse_h_kernel<<<dim3((Nn + 255) / 256, 3), 256, 0, stream>>>(W, T, rs, selpos, h_sel,
                                                                   gcn_b, pool);

    poolgemm_kernel<<<Gg, 128, 0, stream>>>(pool, fc_w, fc_b, def_w, def_b, out);
    xfeat_kernel<<<NTYPE, 256, 0, stream>>>(h_sel, fullcnt, fc_w, fc_b, X);
    mmd_kernel<<<NTYPE, 256, 0, stream>>>(X, fullcnt, losses);
    final_kernel<<<1, 128, 0, stream>>>(losses, out);
}